// Round 9
// baseline (47.270 us; speedup 1.0000x reference)
//
#include <hip/hip_runtime.h>
#include <math.h>

#define BB 8
#define LX 128
#define LY 512
#define DD 256

typedef _Float16 h2t __attribute__((ext_vector_type(2)));

static __device__ __forceinline__ h2t u2h(unsigned int u) {
    h2t r; __builtin_memcpy(&r, &u, 4); return r;
}
static __device__ __forceinline__ unsigned int pk16(float a, float b) {
    h2t h; h.x = (_Float16)a; h.y = (_Float16)b;
    unsigned int u; __builtin_memcpy(&u, &h, 4); return u;
}
static __device__ __forceinline__ h2t rlh(unsigned int v, int l) {
    return u2h((unsigned int)__builtin_amdgcn_readlane((int)v, l));
}

#if defined(__has_builtin) && __has_builtin(__builtin_amdgcn_fdot2)
#define DOT2(a, b, c) __builtin_amdgcn_fdot2((a), (b), (c), false)
#else
#define DOT2(a, b, c) fmaf((float)(a).x, (float)(b).x, fmaf((float)(a).y, (float)(b).y, (c)))
#endif

// ws layout (floats):
//   A16  [B*LX][64] uint2  (row-major d-quads, f16 pairs)  @ 0        (131072 f)
//   CT16 [B][64][LY] uint2 (4 f16 per y per d-quad)        @ 131072   (524288 f)
//   W16  [64] uint2                                        @ 655360   (128 f)
//   Y16p [B][256][256] uint (pairs over y: (2yy,2yy+1))    @ 655488   (524288 f)
#define A16_OFF  0
#define CT16_OFF 131072
#define W16_OFF  655360
#define Y16_OFF  655488

// ---------------------------------------------------------------------------
// Kernel 1: fused GEMMs (fp32 math), f16-packed outputs + y -> f16-pair pack.
//   wgs 0..127   : A16[row][dq] = f16(x_row @ W1[:D] + b1)   (+ W16 on g==0)
//   wgs 128..639 : CT16[b][dq][y] = f16(y_row @ W1[D:])
//   wgs 640..703 : Y16p[b][yy][d] = pack(y[b][2yy][d], y[b][2yy+1][d])
// ---------------------------------------------------------------------------
__global__ __launch_bounds__(256) void gemm_kernel(
    const float* __restrict__ x, const float* __restrict__ y,
    const float* __restrict__ W1, const float* __restrict__ b1,
    const float* __restrict__ W2, float* __restrict__ ws)
{
    const int g = blockIdx.x;
    const int t = threadIdx.x;

    if (g >= 640) {                                  // y -> f16 pair pack
        const int g2 = g - 640;                      // [0,64)
        const int bb = g2 >> 3;
        const int yy0 = (g2 & 7) * 32;
        unsigned int* Yp = (unsigned int*)(ws + Y16_OFF);
        const float* yb = y + (size_t)bb * LY * DD;
        #pragma unroll 4
        for (int i = 0; i < 32; ++i) {
            const int yy = yy0 + i;
            const float v0 = yb[(size_t)(2 * yy) * DD + t];
            const float v1 = yb[(size_t)(2 * yy + 1) * DD + t];
            Yp[((size_t)(bb * 256) + yy) * 256 + t] = pk16(v0, v1);
        }
        return;
    }

    __shared__ float sA[32][20];
    __shared__ float sW[32][128];

    const int tc = t & 31;
    const int tr = t >> 5;

    const bool isA = (g < 128);
    const float* inp;
    const float* wbase;
    int row0, col0;
    if (isA) { col0 = (g & 1) * 128;  row0 = (g >> 1) * 16;  inp = x; wbase = W1; }
    else     { int h = g - 128; col0 = (h & 1) * 128; row0 = (h >> 1) * 16; inp = y; wbase = W1 + DD * DD; }

    float acc[2][4];
    #pragma unroll
    for (int i = 0; i < 2; ++i)
        #pragma unroll
        for (int j = 0; j < 4; ++j) acc[i][j] = 0.f;

    for (int k0 = 0; k0 < DD; k0 += 32) {
        __syncthreads();
        if (t < 128) {
            int row = t >> 3, kq = t & 7;
            const float4 v = *(const float4*)(inp + (size_t)(row0 + row) * DD + k0 + 4 * kq);
            sA[4*kq + 0][row] = v.x;
            sA[4*kq + 1][row] = v.y;
            sA[4*kq + 2][row] = v.z;
            sA[4*kq + 3][row] = v.w;
        }
        #pragma unroll
        for (int i = 0; i < 4; ++i) {
            int flat = t + i * 256;
            int kk = flat >> 5, c4 = flat & 31;
            *(float4*)&sW[kk][4*c4] = *(const float4*)(wbase + (size_t)(k0 + kk) * DD + col0 + 4 * c4);
        }
        __syncthreads();
        #pragma unroll
        for (int k = 0; k < 32; ++k) {
            const float a0 = sA[k][2*tr], a1 = sA[k][2*tr + 1];
            const float4 w4 = *(const float4*)&sW[k][4*tc];
            acc[0][0] = fmaf(a0, w4.x, acc[0][0]);
            acc[0][1] = fmaf(a0, w4.y, acc[0][1]);
            acc[0][2] = fmaf(a0, w4.z, acc[0][2]);
            acc[0][3] = fmaf(a0, w4.w, acc[0][3]);
            acc[1][0] = fmaf(a1, w4.x, acc[1][0]);
            acc[1][1] = fmaf(a1, w4.y, acc[1][1]);
            acc[1][2] = fmaf(a1, w4.z, acc[1][2]);
            acc[1][3] = fmaf(a1, w4.w, acc[1][3]);
        }
    }

    const int dq = (col0 >> 2) + tc;                 // d-quad [0,64)
    if (isA) {
        uint2* A16u2 = (uint2*)(ws + A16_OFF);
        const float4 bv = *(const float4*)(b1 + col0 + 4 * tc);
        #pragma unroll
        for (int i = 0; i < 2; ++i) {
            const int r = row0 + 2 * tr + i;         // global x row [0,1024)
            uint2 st;
            st.x = pk16(acc[i][0] + bv.x, acc[i][1] + bv.y);
            st.y = pk16(acc[i][2] + bv.z, acc[i][3] + bv.w);
            A16u2[(size_t)r * 64 + dq] = st;
        }
        if (g == 0 && t < 64) {                      // build W16 once
            uint2* W16u2 = (uint2*)(ws + W16_OFF);
            const float4 wv = *(const float4*)(W2 + 4 * t);
            uint2 st;
            st.x = pk16(wv.x, wv.y);
            st.y = pk16(wv.z, wv.w);
            W16u2[t] = st;
        }
    } else {
        uint2* Ct16u2 = (uint2*)(ws + CT16_OFF);
        #pragma unroll
        for (int i = 0; i < 2; ++i) {
            const int ry = row0 + 2 * tr + i;        // [0,4096)
            const int bb = ry >> 9, yy = ry & 511;
            uint2 st;
            st.x = pk16(acc[i][0], acc[i][1]);
            st.y = pk16(acc[i][2], acc[i][3]);
            Ct16u2[((size_t)(bb * 64 + dq)) * 512 + yy] = st;
        }
    }
}

// ---------------------------------------------------------------------------
// Kernel 2: fused score+softmax+context+normalize.
// grid 256 = (b = bid&7) x (xg: 4-row group, 32). 512 threads (8 waves).
// Phase 1: wave w owns y = w*64+lane. A rows + W2 in VGPRs, broadcast per-dq
//   via v_readlane; only memory op in the loop is the coalesced ct uint2 load.
// Exit: p pair-packed to f16 via shfl_xor(1) -> LDS (4 KB).
// Phase 2: thread (d = t&255, xh = t>>8) accumulates rows 2xh,2xh+1 over 256
//   y-pairs with v_dot2_f32_f16 on Y16p; writes out = acc/L.
// ---------------------------------------------------------------------------
__global__ __launch_bounds__(512) void fused_kernel(
    const int* __restrict__ ymask, const float* __restrict__ b2,
    const uint2* __restrict__ A16, const uint2* __restrict__ Ct,
    const uint2* __restrict__ W16, const unsigned int* __restrict__ Y16p,
    float* __restrict__ out)
{
    __shared__ __align__(16) unsigned int pp[256][4];   // packed p pairs [yy][row]
    __shared__ __align__(16) float4 Lp[8];

    const int t    = threadIdx.x;
    const int lane = t & 63;
    const int w    = __builtin_amdgcn_readfirstlane(t >> 6);  // wave id 0..7
    const int b    = blockIdx.x & 7;
    const int xg   = blockIdx.x >> 3;            // [0,32), rows xg*4..+3
    const int y    = w * 64 + lane;              // [0,512)

    // ---- distribute A rows + W2 into VGPRs (lane = d-quad) ---------------
    const uint2* Ab = A16 + ((size_t)(b * LX + xg * 4)) * 64;
    uint2 av0 = Ab[lane];
    uint2 av1 = Ab[64 + lane];
    uint2 av2 = Ab[128 + lane];
    uint2 av3 = Ab[192 + lane];
    const uint2 wv = W16[lane];

    const uint2* ctb = Ct + ((size_t)b * 64) * 512 + y;
    const float  b2v = b2[0];
    const bool   msk = ymask[(size_t)b * LY + y] != 0;

    float s0 = 0.f, s1 = 0.f, s2 = 0.f, s3 = 0.f;
    h2t zz; zz.x = (_Float16)0.f; zz.y = (_Float16)0.f;

    #pragma unroll 4
    for (int dq = 0; dq < 64; ++dq) {
        const uint2 cu = ctb[(size_t)dq * 512];          // coalesced, L2-hot
        const h2t c0 = u2h(cu.x), c1 = u2h(cu.y);
        const h2t w0 = rlh(wv.x, dq), w1 = rlh(wv.y, dq);
        {
            const h2t a0 = rlh(av0.x, dq), a1 = rlh(av0.y, dq);
            const h2t h0 = __builtin_elementwise_max(a0 + c0, zz);
            const h2t h1 = __builtin_elementwise_max(a1 + c1, zz);
            s0 = DOT2(h0, w0, s0); s0 = DOT2(h1, w1, s0);
        }
        {
            const h2t a0 = rlh(av1.x, dq), a1 = rlh(av1.y, dq);
            const h2t h0 = __builtin_elementwise_max(a0 + c0, zz);
            const h2t h1 = __builtin_elementwise_max(a1 + c1, zz);
            s1 = DOT2(h0, w0, s1); s1 = DOT2(h1, w1, s1);
        }
        {
            const h2t a0 = rlh(av2.x, dq), a1 = rlh(av2.y, dq);
            const h2t h0 = __builtin_elementwise_max(a0 + c0, zz);
            const h2t h1 = __builtin_elementwise_max(a1 + c1, zz);
            s2 = DOT2(h0, w0, s2); s2 = DOT2(h1, w1, s2);
        }
        {
            const h2t a0 = rlh(av3.x, dq), a1 = rlh(av3.y, dq);
            const h2t h0 = __builtin_elementwise_max(a0 + c0, zz);
            const h2t h1 = __builtin_elementwise_max(a1 + c1, zz);
            s3 = DOT2(h0, w0, s3); s3 = DOT2(h1, w1, s3);
        }
    }

    const float p0 = msk ? 0.f : __expf(s0 + b2v);
    const float p1 = msk ? 0.f : __expf(s1 + b2v);
    const float p2 = msk ? 0.f : __expf(s2 + b2v);
    const float p3 = msk ? 0.f : __expf(s3 + b2v);

    float l0 = p0, l1 = p1, l2 = p2, l3 = p3;
    #pragma unroll
    for (int off = 32; off; off >>= 1) {
        l0 += __shfl_xor(l0, off);
        l1 += __shfl_xor(l1, off);
        l2 += __shfl_xor(l2, off);
        l3 += __shfl_xor(l3, off);
    }

    // pair-pack p with the y+1 neighbor (lane^1), even lanes store uint4
    const float q0 = __shfl_xor(p0, 1);
    const float q1 = __shfl_xor(p1, 1);
    const float q2 = __shfl_xor(p2, 1);
    const float q3 = __shfl_xor(p3, 1);
    if (!(lane & 1)) {
        uint4 st;
        st.x = pk16(p0, q0);
        st.y = pk16(p1, q1);
        st.z = pk16(p2, q2);
        st.w = pk16(p3, q3);
        *(uint4*)&pp[y >> 1][0] = st;
    }
    if (lane == 0) Lp[w] = make_float4(l0, l1, l2, l3);
    __syncthreads();

    // ---- phase 2: rows 2xh, 2xh+1 over 256 y-pairs -----------------------
    const int d  = t & 255;
    const int xh = t >> 8;
    float L0 = 0.f, L1 = 0.f;
    #pragma unroll
    for (int ww = 0; ww < 8; ++ww) {
        const float4 lv = Lp[ww];
        L0 += xh ? lv.z : lv.x;
        L1 += xh ? lv.w : lv.y;
    }

    float a0 = 0.f, a1 = 0.f;
    const unsigned int* Yb = Y16p + ((size_t)b * 256) * 256 + d;
    #pragma unroll 8
    for (int yy = 0; yy < 256; ++yy) {
        const h2t v = u2h(Yb[(size_t)yy * 256]);             // coalesced 4B/lane
        const uint2 pv = *(const uint2*)&pp[yy][2 * xh];     // LDS broadcast b64
        a0 = DOT2(u2h(pv.x), v, a0);
        a1 = DOT2(u2h(pv.y), v, a1);
    }

    const size_t row = (size_t)(b * LX + xg * 4 + 2 * xh);
    out[row * DD + d]       = a0 / L0;
    out[(row + 1) * DD + d] = a1 / L1;
}

// ---------------------------------------------------------------------------
extern "C" void kernel_launch(void* const* d_in, const int* in_sizes, int n_in,
                              void* d_out, int out_size, void* d_ws, size_t ws_size,
                              hipStream_t stream) {
    const float* x     = (const float*)d_in[0];
    const float* y     = (const float*)d_in[1];
    const int*   ymask = (const int*)  d_in[2];
    const float* W1    = (const float*)d_in[3];
    const float* b1    = (const float*)d_in[4];
    const float* W2    = (const float*)d_in[5];
    const float* b2    = (const float*)d_in[6];
    float* ws  = (float*)d_ws;
    float* out = (float*)d_out;

    hipLaunchKernelGGL(gemm_kernel, dim3(704), dim3(256), 0, stream, x, y, W1, b1, W2, ws);
    hipLaunchKernelGGL(fused_kernel, dim3(256), dim3(512), 0, stream,
                       ymask, b2,
                       (const uint2*)(ws + A16_OFF), (const uint2*)(ws + CT16_OFF),
                       (const uint2*)(ws + W16_OFF), (const unsigned int*)(ws + Y16_OFF),
                       out);
}